// Round 10
// baseline (253.032 us; speedup 1.0000x reference)
//
#include <hip/hip_runtime.h>
#include <climits>

// Problem constants (fixed by the reference): B=8192 rows, D=512 features.
#define NB 8192
#define ND 512
#define NSPLIT 32
#define RSTART 64
#define RSPAN ((NB - RSTART + NSPLIT - 1) / NSPLIT)   // 254 columns per range

// ===========================================================================
// Fast path: init -> fused band (computes own stats; z==0 writes ws stats)
//            -> strag -> final, all through d_ws.
// ws layout (floats): rnImg rnTxt rnCr dgSim dgCr mgCr [6*NB]
//            (ints):  negIdx [4*NB], stragCnt [16], stragList [4*NB]
// negIdx is NOT bulk-initialized: band writes INT_MAX per straggler.
// ===========================================================================

__global__ __launch_bounds__(256) void init0_k(float* out, int n, int* stragCnt) {
    int t = threadIdx.x;
    if (t < n) out[t] = 0.0f;
    if (t < 4) stragCnt[t] = 0;
}

__device__ inline void pass_arrays(int z,
        const float* img, const float* txt, const float* cr,
        const float* rnImg, const float* rnTxt, const float* rnCr,
        const float* dgSim, const float* dgCr,
        const float* margin, const float* mgCr,
        const float*& A, const float*& B, const float*& rnA, const float*& rnB,
        const float*& dgA, const float*& mgA) {
    if (z == 0)      { A = img; B = txt; rnA = rnImg; rnB = rnTxt; dgA = dgSim; mgA = margin; }
    else if (z == 1) { A = txt; B = img; rnA = rnTxt; rnB = rnImg; dgA = dgSim; mgA = margin; }
    else if (z == 2) { A = img; B = cr;  rnA = rnImg; rnB = rnCr;  dgA = dgCr;  mgA = mgCr;   }
    else             { A = cr;  B = img; rnA = rnCr;  rnB = rnImg; dgA = dgCr;  mgA = mgCr;   }
}

// Fused band: phase-A per-anchor stats in-block (R2-proven), on-the-fly column
// norms from staging, one 64x64x512 GEMM chunk, first-valid mining, straggler
// registration (negIdx=INT_MAX). z==0 blocks also write ws stat arrays for
// strag_k / final_k (in-order stream: they run strictly later).
__global__ __launch_bounds__(256) void band_k(
        const float* __restrict__ img, const float* __restrict__ txt,
        const float* __restrict__ cr, const int* __restrict__ labels,
        const int* __restrict__ flagp, const float* __restrict__ margin,
        const float* __restrict__ betap,
        float* rnImg, float* rnTxt, float* rnCr,
        float* dgSim, float* dgCr, float* mgCr,
        int* negIdx, int* stragCnt, int* stragList, float* out) {
    __shared__ __align__(16) float As[16][64];
    __shared__ __align__(16) float Bs[16][64];
    __shared__ float aRn[64], aDg[64], aMg[64], colRn[64];
    __shared__ int   aLab[64], colLab[64], resIdx[64];
    __shared__ float blockAcc;

    const int tid = threadIdx.x, z = blockIdx.y, a0 = blockIdx.x * 64;
    const int flag = flagp[0];
    const float* A = (z == 1) ? txt : (z == 3) ? cr : img;
    const float* B = (z == 0) ? txt : (z == 2) ? cr : img;

    // ---- Phase A: per-anchor stats (4 threads per anchor) ----
    {
        int ar = tid >> 2, q = tid & 3;
        int a  = a0 + ar;
        const float4* iv = (const float4*)(img + (size_t)a * ND) + q * 32;
        const float4* tv = (const float4*)(txt + (size_t)a * ND) + q * 32;
        const float4* cv = (const float4*)(cr  + (size_t)a * ND) + q * 32;
        float sii = 0, stt = 0, scc = 0, sit = 0, sic = 0;
        #pragma unroll 4
        for (int i = 0; i < 32; ++i) {
            float4 x = iv[i], y = tv[i], w = cv[i];
            sii += x.x*x.x + x.y*x.y + x.z*x.z + x.w*x.w;
            stt += y.x*y.x + y.y*y.y + y.z*y.z + y.w*y.w;
            scc += w.x*w.x + w.y*w.y + w.z*w.z + w.w*w.w;
            sit += x.x*y.x + x.y*y.y + x.z*y.z + x.w*y.w;
            sic += x.x*w.x + x.y*w.y + x.z*w.z + x.w*w.w;
        }
        sii += __shfl_xor(sii, 1); sii += __shfl_xor(sii, 2);
        stt += __shfl_xor(stt, 1); stt += __shfl_xor(stt, 2);
        scc += __shfl_xor(scc, 1); scc += __shfl_xor(scc, 2);
        sit += __shfl_xor(sit, 1); sit += __shfl_xor(sit, 2);
        sic += __shfl_xor(sic, 1); sic += __shfl_xor(sic, 2);
        if (q == 0) {
            float rnI = 1.0f / (sqrtf(sii) + 1e-8f);
            float rnT = 1.0f / (sqrtf(stt) + 1e-8f);
            float rnC = 1.0f / (sqrtf(scc) + 1e-8f);
            float ds  = sit * rnI * rnT;
            float dc  = sic * rnI * rnC;
            float m   = margin[a];
            float mcr = flag ? (fminf(fabsf(dc) / fabsf(ds), 1.0f) + 1.0f) * m * 0.5f
                             : m * 0.5f;
            if (z == 0) {                       // publish stats for strag/final
                rnImg[a] = rnI; rnTxt[a] = rnT; rnCr[a] = rnC;
                dgSim[a] = ds;  dgCr[a]  = dc;  mgCr[a] = mcr;
            }
            float mg  = (z >= 2) ? mcr : m;
            aRn[ar]  = (z == 1) ? rnT : (z == 3) ? rnC : rnI;
            aDg[ar]  = (z >= 2) ? dc : ds;
            aMg[ar]  = mg;
            aLab[ar] = labels[a];
            resIdx[ar] = (flag && mg < 0.16f) ? -1 : INT_MAX;
        }
        if (tid == 0) blockAcc = 0.0f;
    }
    __syncthreads();

    const int ty4  = (tid >> 4) * 4, tx4 = (tid & 15) * 4;
    const int lrow = tid >> 2,  lk4 = (tid & 3) * 4;

    float acc[4][4];
    #pragma unroll
    for (int i = 0; i < 4; ++i)
        #pragma unroll
        for (int j = 0; j < 4; ++j) acc[i][j] = 0.0f;
    float bssq = 0.0f;                            // column sum-of-squares partial

    for (int kc = 0; kc < ND; kc += 16) {
        __syncthreads();
        float4 va = *(const float4*)(A + (size_t)(a0 + lrow) * ND + kc + lk4);
        float4 vb = *(const float4*)(B + (size_t)lrow * ND + kc + lk4);
        As[lk4 + 0][lrow] = va.x; As[lk4 + 1][lrow] = va.y;
        As[lk4 + 2][lrow] = va.z; As[lk4 + 3][lrow] = va.w;
        Bs[lk4 + 0][lrow] = vb.x; Bs[lk4 + 1][lrow] = vb.y;
        Bs[lk4 + 2][lrow] = vb.z; Bs[lk4 + 3][lrow] = vb.w;
        bssq += vb.x*vb.x + vb.y*vb.y + vb.z*vb.z + vb.w*vb.w;
        __syncthreads();
        #pragma unroll
        for (int k = 0; k < 16; ++k) {
            float4 av = *(const float4*)&As[k][ty4];
            float4 bv = *(const float4*)&Bs[k][tx4];
            float ar[4] = {av.x, av.y, av.z, av.w};
            float br[4] = {bv.x, bv.y, bv.z, bv.w};
            #pragma unroll
            for (int i = 0; i < 4; ++i)
                #pragma unroll
                for (int j = 0; j < 4; ++j)
                    acc[i][j] = fmaf(ar[i], br[j], acc[i][j]);
        }
    }
    // column norms (4 threads per row -> butterfly over lane bits 0-1)
    bssq += __shfl_xor(bssq, 1); bssq += __shfl_xor(bssq, 2);
    __syncthreads();
    if ((tid & 3) == 0) {
        colRn[lrow]  = 1.0f / (sqrtf(bssq) + 1e-8f);
        colLab[lrow] = labels[lrow];
    }
    __syncthreads();

    // predicate pass: first valid (min col) via atomicMin
    #pragma unroll
    for (int i = 0; i < 4; ++i) {
        int r = ty4 + i;
        float mgv = aMg[r];
        if (flag && mgv < 0.16f) continue;
        float dg = aDg[r], rna = aRn[r];
        int la = aLab[r];
        #pragma unroll
        for (int j = 0; j < 4; ++j) {
            int c = tx4 + j;
            if (colLab[c] == la) continue;
            float v  = acc[i][j] * rna * colRn[c];
            float lm = v - dg + mgv;
            if (lm > 0.0f && lm < mgv) atomicMin(&resIdx[r], c);
        }
    }
    __syncthreads();

    // winner pass: unique owner thread of the winning column adds lm
    #pragma unroll
    for (int i = 0; i < 4; ++i) {
        int r = ty4 + i;
        int w = resIdx[r];
        if (w < 0 || w == INT_MAX) continue;
        int c = w - tx4;
        if (c < 0 || c > 3) continue;
        float v  = acc[i][c] * aRn[r] * colRn[w];
        float lm = v - aDg[r] + aMg[r];
        atomicAdd(&blockAcc, lm);
    }
    __syncthreads();

    if (tid < 64 && resIdx[tid] == INT_MAX) {     // unresolved -> straggler
        negIdx[z * NB + a0 + tid] = INT_MAX;      // per-straggler init
        int pos = atomicAdd(&stragCnt[z], 1);
        stragList[z * NB + pos] = a0 + tid;
    }
    if (tid == 0 && blockAcc != 0.0f) {
        float scale = (z >= 2) ? betap[0] : 1.0f;
        atomicAdd(out, blockAcc * scale);
    }
}

__device__ inline float dot8(const float4& a0, const float4& a1,
                             const float4& b0, const float4& b1) {
    return a0.x*b0.x + a0.y*b0.y + a0.z*b0.z + a0.w*b0.w
         + a1.x*b1.x + a1.y*b1.y + a1.z*b1.z + a1.w*b1.w;
}

// Straggler scan v7: R9's rg-major pooled scheduling + explicit 4-column load
// batching: 8 UNCONDITIONAL float4 loads into register arrays (OOB columns
// alias row 0; result discarded by the col<end mask in phase 2), then 4 dots,
// then 4 interleaved shuffle chains. Forces ~32 loads in flight (R9's
// VGPR_Count=28 proved the compiler serialized the paired version).
__global__ __launch_bounds__(256) void strag_k(
        const float* __restrict__ img, const float* __restrict__ txt,
        const float* __restrict__ cr, const int* __restrict__ labels,
        const float* rnImg, const float* rnTxt, const float* rnCr,
        const float* dgSim, const float* dgCr,
        const float* __restrict__ margin, const float* mgCr,
        const int* stragCnt, const int* stragList, int* negIdx) {
    __shared__ float colDot[64];
    __shared__ int   cMin;
    __shared__ int   sharedG;
    const int tid = threadIdx.x;
    const int wv = tid >> 6, lane = tid & 63;

    const int s0c = stragCnt[0], s1c = stragCnt[1];
    const int s2c = stragCnt[2], s3c = stragCnt[3];
    const int ST = s0c + s1c + s2c + s3c;
    const int total = ST * NSPLIT;

    for (int it = blockIdx.x; it < total; it += gridDim.x) {
        int rg = it / ST;                         // rg-major ordering
        int sIdx = it - rg * ST;
        int z, s;
        if (sIdx < s0c)                 { z = 0; s = sIdx; }
        else if ((sIdx -= s0c) < s1c)   { z = 1; s = sIdx; }
        else if ((sIdx -= s1c) < s2c)   { z = 2; s = sIdx; }
        else                            { z = 3; s = sIdx - s2c; }
        const float *A, *B, *rnA, *rnB, *dgA, *mgA;
        pass_arrays(z, img, txt, cr, rnImg, rnTxt, rnCr, dgSim, dgCr,
                    margin, mgCr, A, B, rnA, rnB, dgA, mgA);
        int a = stragList[z * NB + s];
        int* gp = &negIdx[z * NB + a];
        const int start = RSTART + rg * RSPAN;
        const int rEnd = min(start + RSPAN, NB);

        __syncthreads();                          // guard cMin/colDot reuse
        if (tid == 0) { cMin = INT_MAX; sharedG = atomicMin(gp, INT_MAX); }
        __syncthreads();
        int end = min(rEnd, sharedG);             // uniform
        if (start >= end) continue;               // pruned: ~0 cost

        float rna = rnA[a], dgv = dgA[a], mgv = mgA[a];
        int la = labels[a];
        const float4* Av = (const float4*)(A + (size_t)a * ND);
        float4 ar0 = Av[lane], ar1 = Av[lane + 64];

        for (int j0 = start; j0 < end; j0 += 64) {
            // phase 1: 4 waves x 16 cols, in groups of 4 (8 loads batched)
            #pragma unroll
            for (int g = 0; g < 4; ++g) {
                int cbase = j0 + wv * 16 + g * 4;
                float4 b0[4], b1[4];
                #pragma unroll
                for (int q = 0; q < 4; ++q) {
                    int col = cbase + q;
                    const float4* Bv = (col < end)
                        ? (const float4*)(B + (size_t)col * ND)
                        : (const float4*)B;        // safe dummy, masked later
                    b0[q] = Bv[lane]; b1[q] = Bv[lane + 64];
                }
                float d[4];
                #pragma unroll
                for (int q = 0; q < 4; ++q) d[q] = dot8(ar0, ar1, b0[q], b1[q]);
                #pragma unroll
                for (int off = 1; off < 64; off <<= 1) {
                    #pragma unroll
                    for (int q = 0; q < 4; ++q) d[q] += __shfl_xor(d[q], off);
                }
                if (lane == 0) {
                    colDot[wv * 16 + g * 4 + 0] = d[0];
                    colDot[wv * 16 + g * 4 + 1] = d[1];
                    colDot[wv * 16 + g * 4 + 2] = d[2];
                    colDot[wv * 16 + g * 4 + 3] = d[3];
                }
            }
            __syncthreads();
            // phase 2: predicate (tid<64); tid 64 refreshes the global min
            if (tid < 64) {
                int col = j0 + tid;
                if (col < end && labels[col] != la) {
                    float lm = colDot[tid] * rna * rnB[col] - dgv + mgv;
                    if (lm > 0.0f && lm < mgv) atomicMin(&cMin, col);
                }
            } else if (tid == 64) {
                sharedG = atomicMin(gp, INT_MAX); // pure read
            }
            __syncthreads();
            int found = cMin;                     // uniform
            int gmin  = sharedG;                  // uniform
            if (found != INT_MAX) {
                if (tid == 0) atomicMin(gp, found);
                break;                            // first valid in this range
            }
            if (gmin <= start) break;             // another range already won
            if (gmin < end) end = gmin;           // uniform shrink
        }
    }
}

// Recompute winning sim value per straggler, block-reduce, accumulate.
__global__ __launch_bounds__(256) void final_k(
        const float* __restrict__ img, const float* __restrict__ txt,
        const float* __restrict__ cr,
        const float* rnImg, const float* rnTxt, const float* rnCr,
        const float* dgSim, const float* dgCr,
        const float* __restrict__ margin, const float* mgCr,
        const float* __restrict__ betap,
        const int* stragCnt, const int* stragList, const int* negIdx,
        float* out) {
    __shared__ float s4[4];
    const int tid = threadIdx.x, z = blockIdx.y;
    const float *A, *B, *rnA, *rnB, *dgA, *mgA;
    pass_arrays(z, img, txt, cr, rnImg, rnTxt, rnCr, dgSim, dgCr, margin, mgCr,
                A, B, rnA, rnB, dgA, mgA);
    int t = blockIdx.x * 256 + tid;
    float contrib = 0.0f;
    if (t < stragCnt[z]) {
        int a = stragList[z * NB + t];
        int idx = negIdx[z * NB + a];
        if (idx != INT_MAX) {
            const float4* Av = (const float4*)(A + (size_t)a   * ND);
            const float4* Bv = (const float4*)(B + (size_t)idx * ND);
            float d = 0.0f;
            #pragma unroll 8
            for (int i = 0; i < ND / 4; ++i) {
                float4 x = Av[i], y = Bv[i];
                d += x.x*y.x + x.y*y.y + x.z*y.z + x.w*y.w;
            }
            float lm = d * rnA[a] * rnB[idx] - dgA[a] + mgA[a];
            contrib = fmaxf(lm, 0.0f);
        }
    }
    #pragma unroll
    for (int off = 32; off; off >>= 1) contrib += __shfl_xor(contrib, off);
    if ((tid & 63) == 0) s4[tid >> 6] = contrib;
    __syncthreads();
    if (tid == 0) {
        float sum = s4[0] + s4[1] + s4[2] + s4[3];
        if (sum != 0.0f) atomicAdd(out, sum * ((z >= 2) ? betap[0] : 1.0f));
    }
}

// ===========================================================================
// Fallback path (no workspace) — the proven round-3 single-kernel version.
// ===========================================================================

__global__ __launch_bounds__(256) void zero_k(float* out, int n) {
    int g = blockIdx.x * 256 + threadIdx.x;
    if (g < n) out[g] = 0.0f;
}

template <int U>
__device__ void stragScan(const float* __restrict__ A, const float* __restrict__ B,
                          const int* __restrict__ labels, int a0, int u, int scol,
                          const int* sList, int g0,
                          const float* aRn, const float* aDg, const float* aMg,
                          const int* aLab, int* sMin8, int* doneMask,
                          float* blockAcc) {
    const int tid = threadIdx.x;
    float rn_s[U], dg_s[U], mg_s[U];
    int lab_s[U];
    const float4* Av[U];
    #pragma unroll
    for (int s = 0; s < U; ++s) {
        int slot = sList[g0 + (s < u ? s : 0)];
        rn_s[s] = aRn[slot]; dg_s[s] = aDg[slot]; mg_s[s] = aMg[slot];
        lab_s[s] = aLab[slot];
        Av[s] = (const float4*)(A + (size_t)(a0 + slot) * ND);
    }
    if (tid < U) sMin8[tid] = INT_MAX;
    if (tid == 0) *doneMask = 0;
    __syncthreads();
    for (int jb = scol; jb < NB; jb += 256) {
        int j = jb + tid;
        bool jv = (j < NB);
        int mask = *doneMask;
        float dot[U];
        #pragma unroll
        for (int s = 0; s < U; ++s) dot[s] = 0.0f;
        float ssq = 0.0f;
        if (jv) {
            const float4* Bv = (const float4*)(B + (size_t)j * ND);
            #pragma unroll 4
            for (int k4 = 0; k4 < ND / 4; ++k4) {
                float4 b = Bv[k4];
                ssq += b.x*b.x + b.y*b.y + b.z*b.z + b.w*b.w;
                #pragma unroll
                for (int s = 0; s < U; ++s) {
                    float4 a = Av[s][k4];
                    dot[s] += a.x*b.x + a.y*b.y + a.z*b.z + a.w*b.w;
                }
            }
        }
        float rnb = 1.0f / (sqrtf(ssq) + 1e-8f);
        int lj = jv ? labels[j] : -1;
        float lmv[U];
        #pragma unroll
        for (int s = 0; s < U; ++s) {
            lmv[s] = dot[s] * rn_s[s] * rnb - dg_s[s] + mg_s[s];
            if (jv && s < u && !((mask >> s) & 1) && lj != lab_s[s] &&
                lmv[s] > 0.0f && lmv[s] < mg_s[s])
                atomicMin(&sMin8[s], j);
        }
        __syncthreads();
        #pragma unroll
        for (int s = 0; s < U; ++s)
            if (jv && s < u && !((mask >> s) & 1) && sMin8[s] == j)
                atomicAdd(blockAcc, lmv[s]);
        __syncthreads();
        if (tid == 0) {
            int m2 = 0;
            for (int s = 0; s < u; ++s)
                if (sMin8[s] != INT_MAX) m2 |= (1 << s);
            *doneMask = m2;
        }
        __syncthreads();
        if (*doneMask == (1 << u) - 1) break;
    }
}

__global__ __launch_bounds__(256) void mine_k(const float* __restrict__ img,
                                              const float* __restrict__ txt,
                                              const float* __restrict__ cr,
                                              const int*   __restrict__ labels,
                                              const int*   __restrict__ flagp,
                                              const float* __restrict__ margin,
                                              const float* __restrict__ betap,
                                              float* __restrict__ out) {
    __shared__ __align__(16) float As[16][64];
    __shared__ __align__(16) float Bs[16][64];
    __shared__ float aRn[64], aDg[64], aMg[64];
    __shared__ int   aLab[64];
    __shared__ float colRn[64];
    __shared__ int   colLab[64];
    __shared__ int   resIdx[64], prevIdx[64];
    __shared__ int   cnt;
    __shared__ float blockAcc;
    __shared__ int   sList[64];
    __shared__ int   sCnt;
    __shared__ int   sMin8[8];
    __shared__ int   doneMask;

    const int tid  = threadIdx.x;
    const int z    = blockIdx.y;
    const int a0   = blockIdx.x * 64;
    const int flag = flagp[0];
    const float* A = (z == 1) ? txt : (z == 3) ? cr : img;
    const float* B = (z == 0) ? txt : (z == 2) ? cr : img;
    {
        int ar = tid >> 2, q = tid & 3;
        int a  = a0 + ar;
        const float4* iv = (const float4*)(img + (size_t)a * ND) + q * 32;
        const float4* tv = (const float4*)(txt + (size_t)a * ND) + q * 32;
        const float4* cv = (const float4*)(cr  + (size_t)a * ND) + q * 32;
        float sii = 0, stt = 0, scc = 0, sit = 0, sic = 0;
        #pragma unroll 4
        for (int i = 0; i < 32; ++i) {
            float4 x = iv[i], y = tv[i], w = cv[i];
            sii += x.x*x.x + x.y*x.y + x.z*x.z + x.w*x.w;
            stt += y.x*y.x + y.y*y.y + y.z*y.z + y.w*y.w;
            scc += w.x*w.x + w.y*w.y + w.z*w.z + w.w*w.w;
            sit += x.x*y.x + x.y*y.y + x.z*y.z + x.w*y.w;
            sic += x.x*w.x + x.y*w.y + x.z*w.z + x.w*w.w;
        }
        sii += __shfl_xor(sii, 1); sii += __shfl_xor(sii, 2);
        stt += __shfl_xor(stt, 1); stt += __shfl_xor(stt, 2);
        sit += __shfl_xor(sit, 1); sit += __shfl_xor(sit, 2);
        scc += __shfl_xor(scc, 1); scc += __shfl_xor(scc, 2);
        sic += __shfl_xor(sic, 1); sic += __shfl_xor(sic, 2);
        if (q == 0) {
            float rnI = 1.0f / (sqrtf(sii) + 1e-8f);
            float rnT = 1.0f / (sqrtf(stt) + 1e-8f);
            float ds  = sit * rnI * rnT;
            float m   = margin[a];
            float mg, rna, dgv;
            if (z >= 2) {
                float rnC = 1.0f / (sqrtf(scc) + 1e-8f);
                float dc  = sic * rnI * rnC;
                mg = flag ? (fminf(fabsf(dc) / fabsf(ds), 1.0f) + 1.0f) * m * 0.5f
                          : m * 0.5f;
                dgv = dc; rna = (z == 3) ? rnC : rnI;
            } else {
                mg = m; dgv = ds; rna = (z == 1) ? rnT : rnI;
            }
            aRn[ar] = rna; aDg[ar] = dgv; aMg[ar] = mg; aLab[ar] = labels[a];
            resIdx[ar] = (flag && mg < 0.16f) ? -1 : INT_MAX;
        }
        if (tid == 0) blockAcc = 0.0f;
    }
    __syncthreads();
    const int ty4  = (tid >> 4) * 4, tx4 = (tid & 15) * 4;
    const int lrow = tid >> 2,  lk4 = (tid & 3) * 4;
    int bandCols = 0, unresolved = 64;
    for (int jc = 0; jc < 2; ++jc) {
        int j0 = jc * 64;
        float acc[4][4];
        #pragma unroll
        for (int i = 0; i < 4; ++i)
            #pragma unroll
            for (int j = 0; j < 4; ++j) acc[i][j] = 0.0f;
        float bssq = 0.0f;
        for (int kc = 0; kc < ND; kc += 16) {
            __syncthreads();
            float4 va = *(const float4*)(A + (size_t)(a0 + lrow) * ND + kc + lk4);
            float4 vb = *(const float4*)(B + (size_t)(j0 + lrow) * ND + kc + lk4);
            As[lk4 + 0][lrow] = va.x; As[lk4 + 1][lrow] = va.y;
            As[lk4 + 2][lrow] = va.z; As[lk4 + 3][lrow] = va.w;
            Bs[lk4 + 0][lrow] = vb.x; Bs[lk4 + 1][lrow] = vb.y;
            Bs[lk4 + 2][lrow] = vb.z; Bs[lk4 + 3][lrow] = vb.w;
            bssq += vb.x*vb.x + vb.y*vb.y + vb.z*vb.z + vb.w*vb.w;
            __syncthreads();
            #pragma unroll
            for (int k = 0; k < 16; ++k) {
                float4 av = *(const float4*)&As[k][ty4];
                float4 bv = *(const float4*)&Bs[k][tx4];
                float ar[4] = {av.x, av.y, av.z, av.w};
                float br[4] = {bv.x, bv.y, bv.z, bv.w};
                #pragma unroll
                for (int i = 0; i < 4; ++i)
                    #pragma unroll
                    for (int j = 0; j < 4; ++j)
                        acc[i][j] = fmaf(ar[i], br[j], acc[i][j]);
            }
        }
        bssq += __shfl_xor(bssq, 1); bssq += __shfl_xor(bssq, 2);
        __syncthreads();
        if ((tid & 3) == 0) {
            colRn[lrow]  = 1.0f / (sqrtf(bssq) + 1e-8f);
            colLab[lrow] = labels[j0 + lrow];
        }
        if (tid < 64) prevIdx[tid] = resIdx[tid];
        __syncthreads();
        #pragma unroll
        for (int i = 0; i < 4; ++i) {
            int r = ty4 + i;
            if (prevIdx[r] != INT_MAX) continue;
            float dg = aDg[r], mgv = aMg[r], rna = aRn[r];
            int la = aLab[r];
            #pragma unroll
            for (int j = 0; j < 4; ++j) {
                int c = tx4 + j;
                if (colLab[c] == la) continue;
                float v  = acc[i][j] * rna * colRn[c];
                float lm = v - dg + mgv;
                if (lm > 0.0f && lm < mgv) atomicMin(&resIdx[r], j0 + c);
            }
        }
        __syncthreads();
        #pragma unroll
        for (int i = 0; i < 4; ++i) {
            int r = ty4 + i;
            if (prevIdx[r] != INT_MAX) continue;
            int w = resIdx[r];
            if (w == INT_MAX) continue;
            int c = w - j0 - tx4;
            if (c < 0 || c > 3) continue;
            float v  = acc[i][c] * aRn[r] * colRn[tx4 + c];
            float lm = v - aDg[r] + aMg[r];
            atomicAdd(&blockAcc, lm);
        }
        __syncthreads();
        if (tid == 0) cnt = 0;
        __syncthreads();
        if (tid < 64 && resIdx[tid] == INT_MAX) atomicAdd(&cnt, 1);
        __syncthreads();
        unresolved = cnt;
        bandCols = j0 + 64;
        __syncthreads();
        if (unresolved <= 8) break;
    }
    if (unresolved > 0) {
        if (tid == 0) sCnt = 0;
        __syncthreads();
        if (tid < 64 && resIdx[tid] == INT_MAX) {
            int pos = atomicAdd(&sCnt, 1);
            sList[pos] = tid;
        }
        __syncthreads();
        int total = sCnt;
        for (int g0 = 0; g0 < total; g0 += 8) {
            int u = min(8, total - g0);
            if (u == 1)      stragScan<1>(A, B, labels, a0, u, bandCols, sList, g0, aRn, aDg, aMg, aLab, sMin8, &doneMask, &blockAcc);
            else if (u == 2) stragScan<2>(A, B, labels, a0, u, bandCols, sList, g0, aRn, aDg, aMg, aLab, sMin8, &doneMask, &blockAcc);
            else if (u <= 4) stragScan<4>(A, B, labels, a0, u, bandCols, sList, g0, aRn, aDg, aMg, aLab, sMin8, &doneMask, &blockAcc);
            else             stragScan<8>(A, B, labels, a0, u, bandCols, sList, g0, aRn, aDg, aMg, aLab, sMin8, &doneMask, &blockAcc);
            __syncthreads();
        }
    }
    if (tid == 0 && blockAcc != 0.0f) {
        float scale = (z >= 2) ? betap[0] : 1.0f;
        atomicAdd(out, blockAcc * scale);
    }
}

// ===========================================================================

extern "C" void kernel_launch(void* const* d_in, const int* in_sizes, int n_in,
                              void* d_out, int out_size, void* d_ws, size_t ws_size,
                              hipStream_t stream) {
    const float* img    = (const float*)d_in[0];
    const float* txt    = (const float*)d_in[1];
    const float* cr     = (const float*)d_in[2];
    const int*   labels = (const int*)  d_in[3];
    const int*   flagp  = (const int*)  d_in[4];
    const float* marg   = (const float*)d_in[5];
    const float* betap  = (const float*)d_in[6];
    float* out = (float*)d_out;
    (void)in_sizes; (void)n_in;

    const size_t REQ = (size_t)(6 * NB) * 4 + (size_t)(4 * NB) * 4 + 64 +
                       (size_t)(4 * NB) * 4;
    if (ws_size >= REQ) {
        float* wf = (float*)d_ws;
        float* rnImg = wf + 0 * NB;
        float* rnTxt = wf + 1 * NB;
        float* rnCr  = wf + 2 * NB;
        float* dgSim = wf + 3 * NB;
        float* dgCr  = wf + 4 * NB;
        float* mgCr  = wf + 5 * NB;
        int* negIdx    = (int*)(wf + 6 * NB);
        int* stragCnt  = negIdx + 4 * NB;
        int* stragList = stragCnt + 16;

        init0_k<<<dim3(1),            dim3(256), 0, stream>>>(out, out_size, stragCnt);
        band_k <<<dim3(NB / 64, 4),   dim3(256), 0, stream>>>(
            img, txt, cr, labels, flagp, marg, betap,
            rnImg, rnTxt, rnCr, dgSim, dgCr, mgCr, negIdx, stragCnt, stragList, out);
        strag_k<<<dim3(4096),         dim3(256), 0, stream>>>(
            img, txt, cr, labels, rnImg, rnTxt, rnCr, dgSim, dgCr, marg, mgCr,
            stragCnt, stragList, negIdx);
        final_k<<<dim3(NB / 256, 4),  dim3(256), 0, stream>>>(
            img, txt, cr, rnImg, rnTxt, rnCr, dgSim, dgCr, marg, mgCr, betap,
            stragCnt, stragList, negIdx, out);
    } else {
        zero_k<<<dim3((out_size + 255) / 256), dim3(256), 0, stream>>>(out, out_size);
        mine_k<<<dim3(NB / 64, 4), dim3(256), 0, stream>>>(img, txt, cr, labels,
                                                           flagp, marg, betap, out);
    }
}

// Round 11
// 232.004 us; speedup vs baseline: 1.0906x; 1.0906x over previous
//
#include <hip/hip_runtime.h>
#include <climits>

// Problem constants (fixed by the reference): B=8192 rows, D=512 features.
#define NB 8192
#define ND 512
#define NSPLIT 32
#define RSTART 64
#define RSPAN ((NB - RSTART + NSPLIT - 1) / NSPLIT)   // 254 columns per range

// ===========================================================================
// Fast path: stats -> band -> strag -> final through d_ws.
// ws layout (floats): rnImg rnTxt rnCr dgSim dgCr mgCr [6*NB]
//            (ints):  negIdx [4*NB], stragCnt [16], stragList [4*NB]
// ===========================================================================

// Per-row stats + workspace init. 16 threads/row, 16 rows/block, 512 blocks.
__global__ __launch_bounds__(256) void stats_k(
        const float* __restrict__ img, const float* __restrict__ txt,
        const float* __restrict__ cr, const float* __restrict__ margin,
        const int* __restrict__ flagp,
        float* rnImg, float* rnTxt, float* rnCr,
        float* dgSim, float* dgCr, float* mgCr,
        int* negIdx, int* stragCnt, float* out) {
    int tid = threadIdx.x, bid = blockIdx.x;
    int g = bid * 256 + tid;
    if (g < 4 * NB) negIdx[g] = INT_MAX;
    if (bid == 0 && tid < 4) stragCnt[tid] = 0;
    if (bid == 0 && tid == 0) out[0] = 0.0f;

    int r = bid * 16 + (tid >> 4);
    int q = tid & 15;
    const float4* iv = (const float4*)(img + (size_t)r * ND);
    const float4* tv = (const float4*)(txt + (size_t)r * ND);
    const float4* cv = (const float4*)(cr  + (size_t)r * ND);
    float sii = 0, stt = 0, scc = 0, sit = 0, sic = 0;
    #pragma unroll
    for (int i = 0; i < 8; ++i) {                 // lane-contiguous: coalesced
        int k = q + i * 16;
        float4 x = iv[k], y = tv[k], w = cv[k];
        sii += x.x*x.x + x.y*x.y + x.z*x.z + x.w*x.w;
        stt += y.x*y.x + y.y*y.y + y.z*y.z + y.w*y.w;
        scc += w.x*w.x + w.y*w.y + w.z*w.z + w.w*w.w;
        sit += x.x*y.x + x.y*y.y + x.z*y.z + x.w*y.w;
        sic += x.x*w.x + x.y*w.y + x.z*w.z + x.w*w.w;
    }
    #pragma unroll
    for (int off = 1; off < 16; off <<= 1) {
        sii += __shfl_xor(sii, off); stt += __shfl_xor(stt, off);
        scc += __shfl_xor(scc, off); sit += __shfl_xor(sit, off);
        sic += __shfl_xor(sic, off);
    }
    if (q == 0) {
        float rnI = 1.0f / (sqrtf(sii) + 1e-8f);
        float rnT = 1.0f / (sqrtf(stt) + 1e-8f);
        float rnC = 1.0f / (sqrtf(scc) + 1e-8f);
        float ds = sit * rnI * rnT;
        float dc = sic * rnI * rnC;
        float m  = margin[r];
        float mcr = flagp[0] ? (fminf(fabsf(dc) / fabsf(ds), 1.0f) + 1.0f) * m * 0.5f
                             : m * 0.5f;
        rnImg[r] = rnI; rnTxt[r] = rnT; rnCr[r] = rnC;
        dgSim[r] = ds;  dgCr[r]  = dc;  mgCr[r] = mcr;
    }
}

__device__ inline void pass_arrays(int z,
        const float* img, const float* txt, const float* cr,
        const float* rnImg, const float* rnTxt, const float* rnCr,
        const float* dgSim, const float* dgCr,
        const float* margin, const float* mgCr,
        const float*& A, const float*& B, const float*& rnA, const float*& rnB,
        const float*& dgA, const float*& mgA) {
    if (z == 0)      { A = img; B = txt; rnA = rnImg; rnB = rnTxt; dgA = dgSim; mgA = margin; }
    else if (z == 1) { A = txt; B = img; rnA = rnTxt; rnB = rnImg; dgA = dgSim; mgA = margin; }
    else if (z == 2) { A = img; B = cr;  rnA = rnImg; rnB = rnCr;  dgA = dgCr;  mgA = mgCr;   }
    else             { A = cr;  B = img; rnA = rnCr;  rnB = rnImg; dgA = dgCr;  mgA = mgCr;   }
}

// One 64x64 GEMM chunk (cols [0,64)) per 64-anchor block; resolve first-valid,
// add contribution of resolved anchors, register the rest as stragglers.
// (R9 version: ws stats + software-pipelined staging — measured ~20 us.)
__global__ __launch_bounds__(256) void band_k(
        const float* __restrict__ img, const float* __restrict__ txt,
        const float* __restrict__ cr, const int* __restrict__ labels,
        const int* __restrict__ flagp, const float* __restrict__ margin,
        const float* __restrict__ betap,
        const float* rnImg, const float* rnTxt, const float* rnCr,
        const float* dgSim, const float* dgCr, const float* mgCr,
        int* stragCnt, int* stragList, float* out) {
    __shared__ __align__(16) float As[16][64];
    __shared__ __align__(16) float Bs[16][64];
    __shared__ float aRn[64], aDg[64], aMg[64], colRn[64];
    __shared__ int   aLab[64], colLab[64], resIdx[64];
    __shared__ float blockAcc;

    const int tid = threadIdx.x, z = blockIdx.y, a0 = blockIdx.x * 64;
    const int flag = flagp[0];
    const float *A, *B, *rnA, *rnB, *dgA, *mgA;
    pass_arrays(z, img, txt, cr, rnImg, rnTxt, rnCr, dgSim, dgCr, margin, mgCr,
                A, B, rnA, rnB, dgA, mgA);

    if (tid < 64) {
        int a = a0 + tid;
        float mg = mgA[a];
        aRn[tid] = rnA[a]; aDg[tid] = dgA[a]; aMg[tid] = mg;
        aLab[tid] = labels[a];
        colRn[tid] = rnB[tid]; colLab[tid] = labels[tid];
        resIdx[tid] = (flag && mg < 0.16f) ? -1 : INT_MAX;
    }
    if (tid == 0) blockAcc = 0.0f;

    const int ty4  = (tid >> 4) * 4, tx4 = (tid & 15) * 4;
    const int lrow = tid >> 2,  lk4 = (tid & 3) * 4;

    float acc[4][4];
    #pragma unroll
    for (int i = 0; i < 4; ++i)
        #pragma unroll
        for (int j = 0; j < 4; ++j) acc[i][j] = 0.0f;

    // software-pipelined staging: prefetch next kc while computing current
    float4 va = *(const float4*)(A + (size_t)(a0 + lrow) * ND + lk4);
    float4 vb = *(const float4*)(B + (size_t)lrow * ND + lk4);
    for (int kc = 0; kc < ND; kc += 16) {
        __syncthreads();                       // prior compute done
        As[lk4 + 0][lrow] = va.x; As[lk4 + 1][lrow] = va.y;
        As[lk4 + 2][lrow] = va.z; As[lk4 + 3][lrow] = va.w;
        Bs[lk4 + 0][lrow] = vb.x; Bs[lk4 + 1][lrow] = vb.y;
        Bs[lk4 + 2][lrow] = vb.z; Bs[lk4 + 3][lrow] = vb.w;
        if (kc + 16 < ND) {
            va = *(const float4*)(A + (size_t)(a0 + lrow) * ND + kc + 16 + lk4);
            vb = *(const float4*)(B + (size_t)lrow * ND + kc + 16 + lk4);
        }
        __syncthreads();
        #pragma unroll
        for (int k = 0; k < 16; ++k) {
            float4 av = *(const float4*)&As[k][ty4];
            float4 bv = *(const float4*)&Bs[k][tx4];
            float ar[4] = {av.x, av.y, av.z, av.w};
            float br[4] = {bv.x, bv.y, bv.z, bv.w};
            #pragma unroll
            for (int i = 0; i < 4; ++i)
                #pragma unroll
                for (int j = 0; j < 4; ++j)
                    acc[i][j] = fmaf(ar[i], br[j], acc[i][j]);
        }
    }
    __syncthreads();

    // predicate pass: first valid (min col) via atomicMin
    #pragma unroll
    for (int i = 0; i < 4; ++i) {
        int r = ty4 + i;
        float mgv = aMg[r];
        if (flag && mgv < 0.16f) continue;     // pre-resolved: contributes 0
        float dg = aDg[r], rna = aRn[r];
        int la = aLab[r];
        #pragma unroll
        for (int j = 0; j < 4; ++j) {
            int c = tx4 + j;
            if (colLab[c] == la) continue;
            float v  = acc[i][j] * rna * colRn[c];
            float lm = v - dg + mgv;
            if (lm > 0.0f && lm < mgv) atomicMin(&resIdx[r], c);
        }
    }
    __syncthreads();

    // winner pass: unique owner thread of the winning column adds lm
    #pragma unroll
    for (int i = 0; i < 4; ++i) {
        int r = ty4 + i;
        int w = resIdx[r];
        if (w < 0 || w == INT_MAX) continue;
        int c = w - tx4;
        if (c < 0 || c > 3) continue;
        float v  = acc[i][c] * aRn[r] * colRn[w];
        float lm = v - aDg[r] + aMg[r];
        atomicAdd(&blockAcc, lm);
    }
    __syncthreads();

    if (tid < 64 && resIdx[tid] == INT_MAX) {  // unresolved -> global straggler
        int pos = atomicAdd(&stragCnt[z], 1);
        stragList[z * NB + pos] = a0 + tid;
    }
    if (tid == 0 && blockAcc != 0.0f) {
        float scale = (z >= 2) ? betap[0] : 1.0f;
        atomicAdd(out, blockAcc * scale);
    }
}

__device__ inline float dot8(const float4& a0, const float4& a1,
                             const float4& b0, const float4& b1) {
    return a0.x*b0.x + a0.y*b0.y + a0.z*b0.z + a0.w*b0.w
         + a1.x*b1.x + a1.y*b1.y + a1.z*b1.z + a1.w*b1.w;
}

// Straggler scan v8: R10's rg-major pooled scheduling + pre-poll pruning,
// with load batching widened to 8 columns (16 unconditional float4 loads in
// flight; OOB columns alias row 0, masked in phase 2), then 8 dots and 8
// interleaved shuffle chains.
__global__ __launch_bounds__(256) void strag_k(
        const float* __restrict__ img, const float* __restrict__ txt,
        const float* __restrict__ cr, const int* __restrict__ labels,
        const float* rnImg, const float* rnTxt, const float* rnCr,
        const float* dgSim, const float* dgCr,
        const float* __restrict__ margin, const float* mgCr,
        const int* stragCnt, const int* stragList, int* negIdx) {
    __shared__ float colDot[64];
    __shared__ int   cMin;
    __shared__ int   sharedG;
    const int tid = threadIdx.x;
    const int wv = tid >> 6, lane = tid & 63;

    const int s0c = stragCnt[0], s1c = stragCnt[1];
    const int s2c = stragCnt[2], s3c = stragCnt[3];
    const int ST = s0c + s1c + s2c + s3c;
    const int total = ST * NSPLIT;

    for (int it = blockIdx.x; it < total; it += gridDim.x) {
        int rg = it / ST;                         // rg-major ordering
        int sIdx = it - rg * ST;
        int z, s;
        if (sIdx < s0c)                 { z = 0; s = sIdx; }
        else if ((sIdx -= s0c) < s1c)   { z = 1; s = sIdx; }
        else if ((sIdx -= s1c) < s2c)   { z = 2; s = sIdx; }
        else                            { z = 3; s = sIdx - s2c; }
        const float *A, *B, *rnA, *rnB, *dgA, *mgA;
        pass_arrays(z, img, txt, cr, rnImg, rnTxt, rnCr, dgSim, dgCr,
                    margin, mgCr, A, B, rnA, rnB, dgA, mgA);
        int a = stragList[z * NB + s];
        int* gp = &negIdx[z * NB + a];
        const int start = RSTART + rg * RSPAN;
        const int rEnd = min(start + RSPAN, NB);

        __syncthreads();                          // guard cMin/colDot reuse
        if (tid == 0) { cMin = INT_MAX; sharedG = atomicMin(gp, INT_MAX); }
        __syncthreads();
        int end = min(rEnd, sharedG);             // uniform
        if (start >= end) continue;               // pruned: ~0 cost

        float rna = rnA[a], dgv = dgA[a], mgv = mgA[a];
        int la = labels[a];
        const float4* Av = (const float4*)(A + (size_t)a * ND);
        float4 ar0 = Av[lane], ar1 = Av[lane + 64];

        for (int j0 = start; j0 < end; j0 += 64) {
            // phase 1: 4 waves x 16 cols, in 2 groups of 8 (16 loads batched)
            #pragma unroll
            for (int g = 0; g < 2; ++g) {
                int cbase = j0 + wv * 16 + g * 8;
                float4 b0[8], b1[8];
                #pragma unroll
                for (int q = 0; q < 8; ++q) {
                    int col = cbase + q;
                    const float4* Bv = (col < end)
                        ? (const float4*)(B + (size_t)col * ND)
                        : (const float4*)B;        // safe dummy, masked later
                    b0[q] = Bv[lane]; b1[q] = Bv[lane + 64];
                }
                float d[8];
                #pragma unroll
                for (int q = 0; q < 8; ++q) d[q] = dot8(ar0, ar1, b0[q], b1[q]);
                #pragma unroll
                for (int off = 1; off < 64; off <<= 1) {
                    #pragma unroll
                    for (int q = 0; q < 8; ++q) d[q] += __shfl_xor(d[q], off);
                }
                if (lane == 0) {
                    #pragma unroll
                    for (int q = 0; q < 8; ++q)
                        colDot[wv * 16 + g * 8 + q] = d[q];
                }
            }
            __syncthreads();
            // phase 2: predicate (tid<64); tid 64 refreshes the global min
            if (tid < 64) {
                int col = j0 + tid;
                if (col < end && labels[col] != la) {
                    float lm = colDot[tid] * rna * rnB[col] - dgv + mgv;
                    if (lm > 0.0f && lm < mgv) atomicMin(&cMin, col);
                }
            } else if (tid == 64) {
                sharedG = atomicMin(gp, INT_MAX); // pure read
            }
            __syncthreads();
            int found = cMin;                     // uniform
            int gmin  = sharedG;                  // uniform
            if (found != INT_MAX) {
                if (tid == 0) atomicMin(gp, found);
                break;                            // first valid in this range
            }
            if (gmin <= start) break;             // another range already won
            if (gmin < end) end = gmin;           // uniform shrink
        }
    }
}

// Recompute winning sim value per straggler, block-reduce, accumulate.
__global__ __launch_bounds__(256) void final_k(
        const float* __restrict__ img, const float* __restrict__ txt,
        const float* __restrict__ cr,
        const float* rnImg, const float* rnTxt, const float* rnCr,
        const float* dgSim, const float* dgCr,
        const float* __restrict__ margin, const float* mgCr,
        const float* __restrict__ betap,
        const int* stragCnt, const int* stragList, const int* negIdx,
        float* out) {
    __shared__ float s4[4];
    const int tid = threadIdx.x, z = blockIdx.y;
    const float *A, *B, *rnA, *rnB, *dgA, *mgA;
    pass_arrays(z, img, txt, cr, rnImg, rnTxt, rnCr, dgSim, dgCr, margin, mgCr,
                A, B, rnA, rnB, dgA, mgA);
    int t = blockIdx.x * 256 + tid;
    float contrib = 0.0f;
    if (t < stragCnt[z]) {
        int a = stragList[z * NB + t];
        int idx = negIdx[z * NB + a];
        if (idx != INT_MAX) {
            const float4* Av = (const float4*)(A + (size_t)a   * ND);
            const float4* Bv = (const float4*)(B + (size_t)idx * ND);
            float d = 0.0f;
            #pragma unroll 8
            for (int i = 0; i < ND / 4; ++i) {
                float4 x = Av[i], y = Bv[i];
                d += x.x*y.x + x.y*y.y + x.z*y.z + x.w*y.w;
            }
            float lm = d * rnA[a] * rnB[idx] - dgA[a] + mgA[a];
            contrib = fmaxf(lm, 0.0f);
        }
    }
    #pragma unroll
    for (int off = 32; off; off >>= 1) contrib += __shfl_xor(contrib, off);
    if ((tid & 63) == 0) s4[tid >> 6] = contrib;
    __syncthreads();
    if (tid == 0) {
        float sum = s4[0] + s4[1] + s4[2] + s4[3];
        if (sum != 0.0f) atomicAdd(out, sum * ((z >= 2) ? betap[0] : 1.0f));
    }
}

// ===========================================================================
// Fallback path (no workspace) — the proven round-3 single-kernel version.
// ===========================================================================

__global__ __launch_bounds__(256) void zero_k(float* out, int n) {
    int g = blockIdx.x * 256 + threadIdx.x;
    if (g < n) out[g] = 0.0f;
}

template <int U>
__device__ void stragScan(const float* __restrict__ A, const float* __restrict__ B,
                          const int* __restrict__ labels, int a0, int u, int scol,
                          const int* sList, int g0,
                          const float* aRn, const float* aDg, const float* aMg,
                          const int* aLab, int* sMin8, int* doneMask,
                          float* blockAcc) {
    const int tid = threadIdx.x;
    float rn_s[U], dg_s[U], mg_s[U];
    int lab_s[U];
    const float4* Av[U];
    #pragma unroll
    for (int s = 0; s < U; ++s) {
        int slot = sList[g0 + (s < u ? s : 0)];
        rn_s[s] = aRn[slot]; dg_s[s] = aDg[slot]; mg_s[s] = aMg[slot];
        lab_s[s] = aLab[slot];
        Av[s] = (const float4*)(A + (size_t)(a0 + slot) * ND);
    }
    if (tid < U) sMin8[tid] = INT_MAX;
    if (tid == 0) *doneMask = 0;
    __syncthreads();
    for (int jb = scol; jb < NB; jb += 256) {
        int j = jb + tid;
        bool jv = (j < NB);
        int mask = *doneMask;
        float dot[U];
        #pragma unroll
        for (int s = 0; s < U; ++s) dot[s] = 0.0f;
        float ssq = 0.0f;
        if (jv) {
            const float4* Bv = (const float4*)(B + (size_t)j * ND);
            #pragma unroll 4
            for (int k4 = 0; k4 < ND / 4; ++k4) {
                float4 b = Bv[k4];
                ssq += b.x*b.x + b.y*b.y + b.z*b.z + b.w*b.w;
                #pragma unroll
                for (int s = 0; s < U; ++s) {
                    float4 a = Av[s][k4];
                    dot[s] += a.x*b.x + a.y*b.y + a.z*b.z + a.w*b.w;
                }
            }
        }
        float rnb = 1.0f / (sqrtf(ssq) + 1e-8f);
        int lj = jv ? labels[j] : -1;
        float lmv[U];
        #pragma unroll
        for (int s = 0; s < U; ++s) {
            lmv[s] = dot[s] * rn_s[s] * rnb - dg_s[s] + mg_s[s];
            if (jv && s < u && !((mask >> s) & 1) && lj != lab_s[s] &&
                lmv[s] > 0.0f && lmv[s] < mg_s[s])
                atomicMin(&sMin8[s], j);
        }
        __syncthreads();
        #pragma unroll
        for (int s = 0; s < U; ++s)
            if (jv && s < u && !((mask >> s) & 1) && sMin8[s] == j)
                atomicAdd(blockAcc, lmv[s]);
        __syncthreads();
        if (tid == 0) {
            int m2 = 0;
            for (int s = 0; s < u; ++s)
                if (sMin8[s] != INT_MAX) m2 |= (1 << s);
            *doneMask = m2;
        }
        __syncthreads();
        if (*doneMask == (1 << u) - 1) break;
    }
}

__global__ __launch_bounds__(256) void mine_k(const float* __restrict__ img,
                                              const float* __restrict__ txt,
                                              const float* __restrict__ cr,
                                              const int*   __restrict__ labels,
                                              const int*   __restrict__ flagp,
                                              const float* __restrict__ margin,
                                              const float* __restrict__ betap,
                                              float* __restrict__ out) {
    __shared__ __align__(16) float As[16][64];
    __shared__ __align__(16) float Bs[16][64];
    __shared__ float aRn[64], aDg[64], aMg[64];
    __shared__ int   aLab[64];
    __shared__ float colRn[64];
    __shared__ int   colLab[64];
    __shared__ int   resIdx[64], prevIdx[64];
    __shared__ int   cnt;
    __shared__ float blockAcc;
    __shared__ int   sList[64];
    __shared__ int   sCnt;
    __shared__ int   sMin8[8];
    __shared__ int   doneMask;

    const int tid  = threadIdx.x;
    const int z    = blockIdx.y;
    const int a0   = blockIdx.x * 64;
    const int flag = flagp[0];
    const float* A = (z == 1) ? txt : (z == 3) ? cr : img;
    const float* B = (z == 0) ? txt : (z == 2) ? cr : img;
    {
        int ar = tid >> 2, q = tid & 3;
        int a  = a0 + ar;
        const float4* iv = (const float4*)(img + (size_t)a * ND) + q * 32;
        const float4* tv = (const float4*)(txt + (size_t)a * ND) + q * 32;
        const float4* cv = (const float4*)(cr  + (size_t)a * ND) + q * 32;
        float sii = 0, stt = 0, scc = 0, sit = 0, sic = 0;
        #pragma unroll 4
        for (int i = 0; i < 32; ++i) {
            float4 x = iv[i], y = tv[i], w = cv[i];
            sii += x.x*x.x + x.y*x.y + x.z*x.z + x.w*x.w;
            stt += y.x*y.x + y.y*y.y + y.z*y.z + y.w*y.w;
            scc += w.x*w.x + w.y*w.y + w.z*w.z + w.w*w.w;
            sit += x.x*y.x + x.y*y.y + x.z*y.z + x.w*y.w;
            sic += x.x*w.x + x.y*w.y + x.z*w.z + x.w*w.w;
        }
        sii += __shfl_xor(sii, 1); sii += __shfl_xor(sii, 2);
        stt += __shfl_xor(stt, 1); stt += __shfl_xor(stt, 2);
        sit += __shfl_xor(sit, 1); sit += __shfl_xor(sit, 2);
        scc += __shfl_xor(scc, 1); scc += __shfl_xor(scc, 2);
        sic += __shfl_xor(sic, 1); sic += __shfl_xor(sic, 2);
        if (q == 0) {
            float rnI = 1.0f / (sqrtf(sii) + 1e-8f);
            float rnT = 1.0f / (sqrtf(stt) + 1e-8f);
            float ds  = sit * rnI * rnT;
            float m   = margin[a];
            float mg, rna, dgv;
            if (z >= 2) {
                float rnC = 1.0f / (sqrtf(scc) + 1e-8f);
                float dc  = sic * rnI * rnC;
                mg = flag ? (fminf(fabsf(dc) / fabsf(ds), 1.0f) + 1.0f) * m * 0.5f
                          : m * 0.5f;
                dgv = dc; rna = (z == 3) ? rnC : rnI;
            } else {
                mg = m; dgv = ds; rna = (z == 1) ? rnT : rnI;
            }
            aRn[ar] = rna; aDg[ar] = dgv; aMg[ar] = mg; aLab[ar] = labels[a];
            resIdx[ar] = (flag && mg < 0.16f) ? -1 : INT_MAX;
        }
        if (tid == 0) blockAcc = 0.0f;
    }
    __syncthreads();
    const int ty4  = (tid >> 4) * 4, tx4 = (tid & 15) * 4;
    const int lrow = tid >> 2,  lk4 = (tid & 3) * 4;
    int bandCols = 0, unresolved = 64;
    for (int jc = 0; jc < 2; ++jc) {
        int j0 = jc * 64;
        float acc[4][4];
        #pragma unroll
        for (int i = 0; i < 4; ++i)
            #pragma unroll
            for (int j = 0; j < 4; ++j) acc[i][j] = 0.0f;
        float bssq = 0.0f;
        for (int kc = 0; kc < ND; kc += 16) {
            __syncthreads();
            float4 va = *(const float4*)(A + (size_t)(a0 + lrow) * ND + kc + lk4);
            float4 vb = *(const float4*)(B + (size_t)(j0 + lrow) * ND + kc + lk4);
            As[lk4 + 0][lrow] = va.x; As[lk4 + 1][lrow] = va.y;
            As[lk4 + 2][lrow] = va.z; As[lk4 + 3][lrow] = va.w;
            Bs[lk4 + 0][lrow] = vb.x; Bs[lk4 + 1][lrow] = vb.y;
            Bs[lk4 + 2][lrow] = vb.z; Bs[lk4 + 3][lrow] = vb.w;
            bssq += vb.x*vb.x + vb.y*vb.y + vb.z*vb.z + vb.w*vb.w;
            __syncthreads();
            #pragma unroll
            for (int k = 0; k < 16; ++k) {
                float4 av = *(const float4*)&As[k][ty4];
                float4 bv = *(const float4*)&Bs[k][tx4];
                float ar[4] = {av.x, av.y, av.z, av.w};
                float br[4] = {bv.x, bv.y, bv.z, bv.w};
                #pragma unroll
                for (int i = 0; i < 4; ++i)
                    #pragma unroll
                    for (int j = 0; j < 4; ++j)
                        acc[i][j] = fmaf(ar[i], br[j], acc[i][j]);
            }
        }
        bssq += __shfl_xor(bssq, 1); bssq += __shfl_xor(bssq, 2);
        __syncthreads();
        if ((tid & 3) == 0) {
            colRn[lrow]  = 1.0f / (sqrtf(bssq) + 1e-8f);
            colLab[lrow] = labels[j0 + lrow];
        }
        if (tid < 64) prevIdx[tid] = resIdx[tid];
        __syncthreads();
        #pragma unroll
        for (int i = 0; i < 4; ++i) {
            int r = ty4 + i;
            if (prevIdx[r] != INT_MAX) continue;
            float dg = aDg[r], mgv = aMg[r], rna = aRn[r];
            int la = aLab[r];
            #pragma unroll
            for (int j = 0; j < 4; ++j) {
                int c = tx4 + j;
                if (colLab[c] == la) continue;
                float v  = acc[i][j] * rna * colRn[c];
                float lm = v - dg + mgv;
                if (lm > 0.0f && lm < mgv) atomicMin(&resIdx[r], j0 + c);
            }
        }
        __syncthreads();
        #pragma unroll
        for (int i = 0; i < 4; ++i) {
            int r = ty4 + i;
            if (prevIdx[r] != INT_MAX) continue;
            int w = resIdx[r];
            if (w == INT_MAX) continue;
            int c = w - j0 - tx4;
            if (c < 0 || c > 3) continue;
            float v  = acc[i][c] * aRn[r] * colRn[tx4 + c];
            float lm = v - aDg[r] + aMg[r];
            atomicAdd(&blockAcc, lm);
        }
        __syncthreads();
        if (tid == 0) cnt = 0;
        __syncthreads();
        if (tid < 64 && resIdx[tid] == INT_MAX) atomicAdd(&cnt, 1);
        __syncthreads();
        unresolved = cnt;
        bandCols = j0 + 64;
        __syncthreads();
        if (unresolved <= 8) break;
    }
    if (unresolved > 0) {
        if (tid == 0) sCnt = 0;
        __syncthreads();
        if (tid < 64 && resIdx[tid] == INT_MAX) {
            int pos = atomicAdd(&sCnt, 1);
            sList[pos] = tid;
        }
        __syncthreads();
        int total = sCnt;
        for (int g0 = 0; g0 < total; g0 += 8) {
            int u = min(8, total - g0);
            if (u == 1)      stragScan<1>(A, B, labels, a0, u, bandCols, sList, g0, aRn, aDg, aMg, aLab, sMin8, &doneMask, &blockAcc);
            else if (u == 2) stragScan<2>(A, B, labels, a0, u, bandCols, sList, g0, aRn, aDg, aMg, aLab, sMin8, &doneMask, &blockAcc);
            else if (u <= 4) stragScan<4>(A, B, labels, a0, u, bandCols, sList, g0, aRn, aDg, aMg, aLab, sMin8, &doneMask, &blockAcc);
            else             stragScan<8>(A, B, labels, a0, u, bandCols, sList, g0, aRn, aDg, aMg, aLab, sMin8, &doneMask, &blockAcc);
            __syncthreads();
        }
    }
    if (tid == 0 && blockAcc != 0.0f) {
        float scale = (z >= 2) ? betap[0] : 1.0f;
        atomicAdd(out, blockAcc * scale);
    }
}

// ===========================================================================

extern "C" void kernel_launch(void* const* d_in, const int* in_sizes, int n_in,
                              void* d_out, int out_size, void* d_ws, size_t ws_size,
                              hipStream_t stream) {
    const float* img    = (const float*)d_in[0];
    const float* txt    = (const float*)d_in[1];
    const float* cr     = (const float*)d_in[2];
    const int*   labels = (const int*)  d_in[3];
    const int*   flagp  = (const int*)  d_in[4];
    const float* marg   = (const float*)d_in[5];
    const float* betap  = (const float*)d_in[6];
    float* out = (float*)d_out;
    (void)in_sizes; (void)n_in;

    const size_t REQ = (size_t)(6 * NB) * 4 + (size_t)(4 * NB) * 4 + 64 +
                       (size_t)(4 * NB) * 4;
    if (ws_size >= REQ) {
        float* wf = (float*)d_ws;
        float* rnImg = wf + 0 * NB;
        float* rnTxt = wf + 1 * NB;
        float* rnCr  = wf + 2 * NB;
        float* dgSim = wf + 3 * NB;
        float* dgCr  = wf + 4 * NB;
        float* mgCr  = wf + 5 * NB;
        int* negIdx    = (int*)(wf + 6 * NB);
        int* stragCnt  = negIdx + 4 * NB;
        int* stragList = stragCnt + 16;

        stats_k<<<dim3(NB / 16),      dim3(256), 0, stream>>>(
            img, txt, cr, marg, flagp,
            rnImg, rnTxt, rnCr, dgSim, dgCr, mgCr, negIdx, stragCnt, out);
        band_k <<<dim3(NB / 64, 4),   dim3(256), 0, stream>>>(
            img, txt, cr, labels, flagp, marg, betap,
            rnImg, rnTxt, rnCr, dgSim, dgCr, mgCr, stragCnt, stragList, out);
        strag_k<<<dim3(4096),         dim3(256), 0, stream>>>(
            img, txt, cr, labels, rnImg, rnTxt, rnCr, dgSim, dgCr, marg, mgCr,
            stragCnt, stragList, negIdx);
        final_k<<<dim3(NB / 256, 4),  dim3(256), 0, stream>>>(
            img, txt, cr, rnImg, rnTxt, rnCr, dgSim, dgCr, marg, mgCr, betap,
            stragCnt, stragList, negIdx, out);
    } else {
        zero_k<<<dim3((out_size + 255) / 256), dim3(256), 0, stream>>>(out, out_size);
        mine_k<<<dim3(NB / 64, 4), dim3(256), 0, stream>>>(img, txt, cr, labels,
                                                           flagp, marg, betap, out);
    }
}

// Round 12
// 221.599 us; speedup vs baseline: 1.1418x; 1.0470x over previous
//
#include <hip/hip_runtime.h>
#include <climits>

// Problem constants (fixed by the reference): B=8192 rows, D=512 features.
#define NB 8192
#define ND 512
#define NSPLIT 32
#define RSTART 64
#define RSPAN ((NB - RSTART + NSPLIT - 1) / NSPLIT)   // 254 columns per range

// ===========================================================================
// Fast path: stats -> band -> strag -> final through d_ws.
// ws layout (floats): rnImg rnTxt rnCr dgSim dgCr mgCr [6*NB]
//            (ints):  negIdx [4*NB], stragCnt [16], stragList [4*NB]
// ===========================================================================

// Per-row stats + workspace init. 16 threads/row, 16 rows/block, 512 blocks.
__global__ __launch_bounds__(256) void stats_k(
        const float* __restrict__ img, const float* __restrict__ txt,
        const float* __restrict__ cr, const float* __restrict__ margin,
        const int* __restrict__ flagp,
        float* rnImg, float* rnTxt, float* rnCr,
        float* dgSim, float* dgCr, float* mgCr,
        int* negIdx, int* stragCnt, float* out) {
    int tid = threadIdx.x, bid = blockIdx.x;
    int g = bid * 256 + tid;
    if (g < 4 * NB) negIdx[g] = INT_MAX;
    if (bid == 0 && tid < 8) stragCnt[tid] = 0;
    if (bid == 0 && tid == 0) out[0] = 0.0f;

    int r = bid * 16 + (tid >> 4);
    int q = tid & 15;
    const float4* iv = (const float4*)(img + (size_t)r * ND);
    const float4* tv = (const float4*)(txt + (size_t)r * ND);
    const float4* cv = (const float4*)(cr  + (size_t)r * ND);
    float sii = 0, stt = 0, scc = 0, sit = 0, sic = 0;
    #pragma unroll
    for (int i = 0; i < 8; ++i) {                 // lane-contiguous: coalesced
        int k = q + i * 16;
        float4 x = iv[k], y = tv[k], w = cv[k];
        sii += x.x*x.x + x.y*x.y + x.z*x.z + x.w*x.w;
        stt += y.x*y.x + y.y*y.y + y.z*y.z + y.w*y.w;
        scc += w.x*w.x + w.y*w.y + w.z*w.z + w.w*w.w;
        sit += x.x*y.x + x.y*y.y + x.z*y.z + x.w*y.w;
        sic += x.x*w.x + x.y*w.y + x.z*w.z + x.w*w.w;
    }
    #pragma unroll
    for (int off = 1; off < 16; off <<= 1) {
        sii += __shfl_xor(sii, off); stt += __shfl_xor(stt, off);
        scc += __shfl_xor(scc, off); sit += __shfl_xor(sit, off);
        sic += __shfl_xor(sic, off);
    }
    if (q == 0) {
        float rnI = 1.0f / (sqrtf(sii) + 1e-8f);
        float rnT = 1.0f / (sqrtf(stt) + 1e-8f);
        float rnC = 1.0f / (sqrtf(scc) + 1e-8f);
        float ds = sit * rnI * rnT;
        float dc = sic * rnI * rnC;
        float m  = margin[r];
        float mcr = flagp[0] ? (fminf(fabsf(dc) / fabsf(ds), 1.0f) + 1.0f) * m * 0.5f
                             : m * 0.5f;
        rnImg[r] = rnI; rnTxt[r] = rnT; rnCr[r] = rnC;
        dgSim[r] = ds;  dgCr[r]  = dc;  mgCr[r] = mcr;
    }
}

__device__ inline void pass_arrays(int z,
        const float* img, const float* txt, const float* cr,
        const float* rnImg, const float* rnTxt, const float* rnCr,
        const float* dgSim, const float* dgCr,
        const float* margin, const float* mgCr,
        const float*& A, const float*& B, const float*& rnA, const float*& rnB,
        const float*& dgA, const float*& mgA) {
    if (z == 0)      { A = img; B = txt; rnA = rnImg; rnB = rnTxt; dgA = dgSim; mgA = margin; }
    else if (z == 1) { A = txt; B = img; rnA = rnTxt; rnB = rnImg; dgA = dgSim; mgA = margin; }
    else if (z == 2) { A = img; B = cr;  rnA = rnImg; rnB = rnCr;  dgA = dgCr;  mgA = mgCr;   }
    else             { A = cr;  B = img; rnA = rnCr;  rnB = rnImg; dgA = dgCr;  mgA = mgCr;   }
}

// One 64x64 GEMM chunk (cols [0,64)) per 64-anchor block; resolve first-valid,
// add contribution of resolved anchors, register the rest as stragglers.
// (R9 version: ws stats + software-pipelined staging — measured ~20 us.)
__global__ __launch_bounds__(256) void band_k(
        const float* __restrict__ img, const float* __restrict__ txt,
        const float* __restrict__ cr, const int* __restrict__ labels,
        const int* __restrict__ flagp, const float* __restrict__ margin,
        const float* __restrict__ betap,
        const float* rnImg, const float* rnTxt, const float* rnCr,
        const float* dgSim, const float* dgCr, const float* mgCr,
        int* stragCnt, int* stragList, float* out) {
    __shared__ __align__(16) float As[16][64];
    __shared__ __align__(16) float Bs[16][64];
    __shared__ float aRn[64], aDg[64], aMg[64], colRn[64];
    __shared__ int   aLab[64], colLab[64], resIdx[64];
    __shared__ float blockAcc;

    const int tid = threadIdx.x, z = blockIdx.y, a0 = blockIdx.x * 64;
    const int flag = flagp[0];
    const float *A, *B, *rnA, *rnB, *dgA, *mgA;
    pass_arrays(z, img, txt, cr, rnImg, rnTxt, rnCr, dgSim, dgCr, margin, mgCr,
                A, B, rnA, rnB, dgA, mgA);

    if (tid < 64) {
        int a = a0 + tid;
        float mg = mgA[a];
        aRn[tid] = rnA[a]; aDg[tid] = dgA[a]; aMg[tid] = mg;
        aLab[tid] = labels[a];
        colRn[tid] = rnB[tid]; colLab[tid] = labels[tid];
        resIdx[tid] = (flag && mg < 0.16f) ? -1 : INT_MAX;
    }
    if (tid == 0) blockAcc = 0.0f;

    const int ty4  = (tid >> 4) * 4, tx4 = (tid & 15) * 4;
    const int lrow = tid >> 2,  lk4 = (tid & 3) * 4;

    float acc[4][4];
    #pragma unroll
    for (int i = 0; i < 4; ++i)
        #pragma unroll
        for (int j = 0; j < 4; ++j) acc[i][j] = 0.0f;

    // software-pipelined staging: prefetch next kc while computing current
    float4 va = *(const float4*)(A + (size_t)(a0 + lrow) * ND + lk4);
    float4 vb = *(const float4*)(B + (size_t)lrow * ND + lk4);
    for (int kc = 0; kc < ND; kc += 16) {
        __syncthreads();                       // prior compute done
        As[lk4 + 0][lrow] = va.x; As[lk4 + 1][lrow] = va.y;
        As[lk4 + 2][lrow] = va.z; As[lk4 + 3][lrow] = va.w;
        Bs[lk4 + 0][lrow] = vb.x; Bs[lk4 + 1][lrow] = vb.y;
        Bs[lk4 + 2][lrow] = vb.z; Bs[lk4 + 3][lrow] = vb.w;
        if (kc + 16 < ND) {
            va = *(const float4*)(A + (size_t)(a0 + lrow) * ND + kc + 16 + lk4);
            vb = *(const float4*)(B + (size_t)lrow * ND + kc + 16 + lk4);
        }
        __syncthreads();
        #pragma unroll
        for (int k = 0; k < 16; ++k) {
            float4 av = *(const float4*)&As[k][ty4];
            float4 bv = *(const float4*)&Bs[k][tx4];
            float ar[4] = {av.x, av.y, av.z, av.w};
            float br[4] = {bv.x, bv.y, bv.z, bv.w};
            #pragma unroll
            for (int i = 0; i < 4; ++i)
                #pragma unroll
                for (int j = 0; j < 4; ++j)
                    acc[i][j] = fmaf(ar[i], br[j], acc[i][j]);
        }
    }
    __syncthreads();

    // predicate pass: first valid (min col) via atomicMin
    #pragma unroll
    for (int i = 0; i < 4; ++i) {
        int r = ty4 + i;
        float mgv = aMg[r];
        if (flag && mgv < 0.16f) continue;     // pre-resolved: contributes 0
        float dg = aDg[r], rna = aRn[r];
        int la = aLab[r];
        #pragma unroll
        for (int j = 0; j < 4; ++j) {
            int c = tx4 + j;
            if (colLab[c] == la) continue;
            float v  = acc[i][j] * rna * colRn[c];
            float lm = v - dg + mgv;
            if (lm > 0.0f && lm < mgv) atomicMin(&resIdx[r], c);
        }
    }
    __syncthreads();

    // winner pass: unique owner thread of the winning column adds lm
    #pragma unroll
    for (int i = 0; i < 4; ++i) {
        int r = ty4 + i;
        int w = resIdx[r];
        if (w < 0 || w == INT_MAX) continue;
        int c = w - tx4;
        if (c < 0 || c > 3) continue;
        float v  = acc[i][c] * aRn[r] * colRn[w];
        float lm = v - aDg[r] + aMg[r];
        atomicAdd(&blockAcc, lm);
    }
    __syncthreads();

    if (tid < 64 && resIdx[tid] == INT_MAX) {  // unresolved -> global straggler
        int pos = atomicAdd(&stragCnt[z], 1);
        stragList[z * NB + pos] = a0 + tid;
    }
    if (tid == 0 && blockAcc != 0.0f) {
        float scale = (z >= 2) ? betap[0] : 1.0f;
        atomicAdd(out, blockAcc * scale);
    }
}

__device__ inline float dot8(const float4& a0, const float4& a1,
                             const float4& b0, const float4& b1) {
    return a0.x*b0.x + a0.y*b0.y + a0.z*b0.z + a0.w*b0.w
         + a1.x*b1.x + a1.y*b1.y + a1.z*b1.z + a1.w*b1.w;
}

// Straggler scan v9: identical inner loop to R11 (batch-8 loads, rg-major,
// pre-poll pruning) but launched on a 16384-block grid so (nearly) every
// item gets its OWN block — removes the static grid-stride queueing where
// active items waited behind a block's earlier items. Blocks beyond `total`
// exit after 4 scalar loads; ascending blockIdx dispatch preserves rg-major
// publish-before-deep-ranges ordering.
__global__ __launch_bounds__(256) void strag_k(
        const float* __restrict__ img, const float* __restrict__ txt,
        const float* __restrict__ cr, const int* __restrict__ labels,
        const float* rnImg, const float* rnTxt, const float* rnCr,
        const float* dgSim, const float* dgCr,
        const float* __restrict__ margin, const float* mgCr,
        const int* stragCnt, const int* stragList, int* negIdx) {
    __shared__ float colDot[64];
    __shared__ int   cMin;
    __shared__ int   sharedG;
    const int tid = threadIdx.x;
    const int wv = tid >> 6, lane = tid & 63;

    const int s0c = stragCnt[0], s1c = stragCnt[1];
    const int s2c = stragCnt[2], s3c = stragCnt[3];
    const int ST = s0c + s1c + s2c + s3c;
    const int total = ST * NSPLIT;

    for (int it = blockIdx.x; it < total; it += gridDim.x) {
        int rg = it / ST;                         // rg-major ordering
        int sIdx = it - rg * ST;
        int z, s;
        if (sIdx < s0c)                 { z = 0; s = sIdx; }
        else if ((sIdx -= s0c) < s1c)   { z = 1; s = sIdx; }
        else if ((sIdx -= s1c) < s2c)   { z = 2; s = sIdx; }
        else                            { z = 3; s = sIdx - s2c; }
        const float *A, *B, *rnA, *rnB, *dgA, *mgA;
        pass_arrays(z, img, txt, cr, rnImg, rnTxt, rnCr, dgSim, dgCr,
                    margin, mgCr, A, B, rnA, rnB, dgA, mgA);
        int a = stragList[z * NB + s];
        int* gp = &negIdx[z * NB + a];
        const int start = RSTART + rg * RSPAN;
        const int rEnd = min(start + RSPAN, NB);

        __syncthreads();                          // guard cMin/colDot reuse
        if (tid == 0) { cMin = INT_MAX; sharedG = atomicMin(gp, INT_MAX); }
        __syncthreads();
        int end = min(rEnd, sharedG);             // uniform
        if (start >= end) continue;               // pruned: ~0 cost

        float rna = rnA[a], dgv = dgA[a], mgv = mgA[a];
        int la = labels[a];
        const float4* Av = (const float4*)(A + (size_t)a * ND);
        float4 ar0 = Av[lane], ar1 = Av[lane + 64];

        for (int j0 = start; j0 < end; j0 += 64) {
            // phase 1: 4 waves x 16 cols, in 2 groups of 8 (16 loads batched)
            #pragma unroll
            for (int g = 0; g < 2; ++g) {
                int cbase = j0 + wv * 16 + g * 8;
                float4 b0[8], b1[8];
                #pragma unroll
                for (int q = 0; q < 8; ++q) {
                    int col = cbase + q;
                    const float4* Bv = (col < end)
                        ? (const float4*)(B + (size_t)col * ND)
                        : (const float4*)B;        // safe dummy, masked later
                    b0[q] = Bv[lane]; b1[q] = Bv[lane + 64];
                }
                float d[8];
                #pragma unroll
                for (int q = 0; q < 8; ++q) d[q] = dot8(ar0, ar1, b0[q], b1[q]);
                #pragma unroll
                for (int off = 1; off < 64; off <<= 1) {
                    #pragma unroll
                    for (int q = 0; q < 8; ++q) d[q] += __shfl_xor(d[q], off);
                }
                if (lane == 0) {
                    #pragma unroll
                    for (int q = 0; q < 8; ++q)
                        colDot[wv * 16 + g * 8 + q] = d[q];
                }
            }
            __syncthreads();
            // phase 2: predicate (tid<64); tid 64 refreshes the global min
            if (tid < 64) {
                int col = j0 + tid;
                if (col < end && labels[col] != la) {
                    float lm = colDot[tid] * rna * rnB[col] - dgv + mgv;
                    if (lm > 0.0f && lm < mgv) atomicMin(&cMin, col);
                }
            } else if (tid == 64) {
                sharedG = atomicMin(gp, INT_MAX); // pure read
            }
            __syncthreads();
            int found = cMin;                     // uniform
            int gmin  = sharedG;                  // uniform
            if (found != INT_MAX) {
                if (tid == 0) atomicMin(gp, found);
                break;                            // first valid in this range
            }
            if (gmin <= start) break;             // another range already won
            if (gmin < end) end = gmin;           // uniform shrink
        }
    }
}

// Recompute winning sim value per straggler, block-reduce, accumulate.
__global__ __launch_bounds__(256) void final_k(
        const float* __restrict__ img, const float* __restrict__ txt,
        const float* __restrict__ cr,
        const float* rnImg, const float* rnTxt, const float* rnCr,
        const float* dgSim, const float* dgCr,
        const float* __restrict__ margin, const float* mgCr,
        const float* __restrict__ betap,
        const int* stragCnt, const int* stragList, const int* negIdx,
        float* out) {
    __shared__ float s4[4];
    const int tid = threadIdx.x, z = blockIdx.y;
    const float *A, *B, *rnA, *rnB, *dgA, *mgA;
    pass_arrays(z, img, txt, cr, rnImg, rnTxt, rnCr, dgSim, dgCr, margin, mgCr,
                A, B, rnA, rnB, dgA, mgA);
    int t = blockIdx.x * 256 + tid;
    float contrib = 0.0f;
    if (t < stragCnt[z]) {
        int a = stragList[z * NB + t];
        int idx = negIdx[z * NB + a];
        if (idx != INT_MAX) {
            const float4* Av = (const float4*)(A + (size_t)a   * ND);
            const float4* Bv = (const float4*)(B + (size_t)idx * ND);
            float d = 0.0f;
            #pragma unroll 8
            for (int i = 0; i < ND / 4; ++i) {
                float4 x = Av[i], y = Bv[i];
                d += x.x*y.x + x.y*y.y + x.z*y.z + x.w*y.w;
            }
            float lm = d * rnA[a] * rnB[idx] - dgA[a] + mgA[a];
            contrib = fmaxf(lm, 0.0f);
        }
    }
    #pragma unroll
    for (int off = 32; off; off >>= 1) contrib += __shfl_xor(contrib, off);
    if ((tid & 63) == 0) s4[tid >> 6] = contrib;
    __syncthreads();
    if (tid == 0) {
        float sum = s4[0] + s4[1] + s4[2] + s4[3];
        if (sum != 0.0f) atomicAdd(out, sum * ((z >= 2) ? betap[0] : 1.0f));
    }
}

// ===========================================================================
// Fallback path (no workspace) — the proven round-3 single-kernel version.
// ===========================================================================

__global__ __launch_bounds__(256) void zero_k(float* out, int n) {
    int g = blockIdx.x * 256 + threadIdx.x;
    if (g < n) out[g] = 0.0f;
}

template <int U>
__device__ void stragScan(const float* __restrict__ A, const float* __restrict__ B,
                          const int* __restrict__ labels, int a0, int u, int scol,
                          const int* sList, int g0,
                          const float* aRn, const float* aDg, const float* aMg,
                          const int* aLab, int* sMin8, int* doneMask,
                          float* blockAcc) {
    const int tid = threadIdx.x;
    float rn_s[U], dg_s[U], mg_s[U];
    int lab_s[U];
    const float4* Av[U];
    #pragma unroll
    for (int s = 0; s < U; ++s) {
        int slot = sList[g0 + (s < u ? s : 0)];
        rn_s[s] = aRn[slot]; dg_s[s] = aDg[slot]; mg_s[s] = aMg[slot];
        lab_s[s] = aLab[slot];
        Av[s] = (const float4*)(A + (size_t)(a0 + slot) * ND);
    }
    if (tid < U) sMin8[tid] = INT_MAX;
    if (tid == 0) *doneMask = 0;
    __syncthreads();
    for (int jb = scol; jb < NB; jb += 256) {
        int j = jb + tid;
        bool jv = (j < NB);
        int mask = *doneMask;
        float dot[U];
        #pragma unroll
        for (int s = 0; s < U; ++s) dot[s] = 0.0f;
        float ssq = 0.0f;
        if (jv) {
            const float4* Bv = (const float4*)(B + (size_t)j * ND);
            #pragma unroll 4
            for (int k4 = 0; k4 < ND / 4; ++k4) {
                float4 b = Bv[k4];
                ssq += b.x*b.x + b.y*b.y + b.z*b.z + b.w*b.w;
                #pragma unroll
                for (int s = 0; s < U; ++s) {
                    float4 a = Av[s][k4];
                    dot[s] += a.x*b.x + a.y*b.y + a.z*b.z + a.w*b.w;
                }
            }
        }
        float rnb = 1.0f / (sqrtf(ssq) + 1e-8f);
        int lj = jv ? labels[j] : -1;
        float lmv[U];
        #pragma unroll
        for (int s = 0; s < U; ++s) {
            lmv[s] = dot[s] * rn_s[s] * rnb - dg_s[s] + mg_s[s];
            if (jv && s < u && !((mask >> s) & 1) && lj != lab_s[s] &&
                lmv[s] > 0.0f && lmv[s] < mg_s[s])
                atomicMin(&sMin8[s], j);
        }
        __syncthreads();
        #pragma unroll
        for (int s = 0; s < U; ++s)
            if (jv && s < u && !((mask >> s) & 1) && sMin8[s] == j)
                atomicAdd(blockAcc, lmv[s]);
        __syncthreads();
        if (tid == 0) {
            int m2 = 0;
            for (int s = 0; s < u; ++s)
                if (sMin8[s] != INT_MAX) m2 |= (1 << s);
            *doneMask = m2;
        }
        __syncthreads();
        if (*doneMask == (1 << u) - 1) break;
    }
}

__global__ __launch_bounds__(256) void mine_k(const float* __restrict__ img,
                                              const float* __restrict__ txt,
                                              const float* __restrict__ cr,
                                              const int*   __restrict__ labels,
                                              const int*   __restrict__ flagp,
                                              const float* __restrict__ margin,
                                              const float* __restrict__ betap,
                                              float* __restrict__ out) {
    __shared__ __align__(16) float As[16][64];
    __shared__ __align__(16) float Bs[16][64];
    __shared__ float aRn[64], aDg[64], aMg[64];
    __shared__ int   aLab[64];
    __shared__ float colRn[64];
    __shared__ int   colLab[64];
    __shared__ int   resIdx[64], prevIdx[64];
    __shared__ int   cnt;
    __shared__ float blockAcc;
    __shared__ int   sList[64];
    __shared__ int   sCnt;
    __shared__ int   sMin8[8];
    __shared__ int   doneMask;

    const int tid  = threadIdx.x;
    const int z    = blockIdx.y;
    const int a0   = blockIdx.x * 64;
    const int flag = flagp[0];
    const float* A = (z == 1) ? txt : (z == 3) ? cr : img;
    const float* B = (z == 0) ? txt : (z == 2) ? cr : img;
    {
        int ar = tid >> 2, q = tid & 3;
        int a  = a0 + ar;
        const float4* iv = (const float4*)(img + (size_t)a * ND) + q * 32;
        const float4* tv = (const float4*)(txt + (size_t)a * ND) + q * 32;
        const float4* cv = (const float4*)(cr  + (size_t)a * ND) + q * 32;
        float sii = 0, stt = 0, scc = 0, sit = 0, sic = 0;
        #pragma unroll 4
        for (int i = 0; i < 32; ++i) {
            float4 x = iv[i], y = tv[i], w = cv[i];
            sii += x.x*x.x + x.y*x.y + x.z*x.z + x.w*x.w;
            stt += y.x*y.x + y.y*y.y + y.z*y.z + y.w*y.w;
            scc += w.x*w.x + w.y*w.y + w.z*w.z + w.w*w.w;
            sit += x.x*y.x + x.y*y.y + x.z*y.z + x.w*y.w;
            sic += x.x*w.x + x.y*w.y + x.z*w.z + x.w*w.w;
        }
        sii += __shfl_xor(sii, 1); sii += __shfl_xor(sii, 2);
        stt += __shfl_xor(stt, 1); stt += __shfl_xor(stt, 2);
        sit += __shfl_xor(sit, 1); sit += __shfl_xor(sit, 2);
        scc += __shfl_xor(scc, 1); scc += __shfl_xor(scc, 2);
        sic += __shfl_xor(sic, 1); sic += __shfl_xor(sic, 2);
        if (q == 0) {
            float rnI = 1.0f / (sqrtf(sii) + 1e-8f);
            float rnT = 1.0f / (sqrtf(stt) + 1e-8f);
            float ds  = sit * rnI * rnT;
            float m   = margin[a];
            float mg, rna, dgv;
            if (z >= 2) {
                float rnC = 1.0f / (sqrtf(scc) + 1e-8f);
                float dc  = sic * rnI * rnC;
                mg = flag ? (fminf(fabsf(dc) / fabsf(ds), 1.0f) + 1.0f) * m * 0.5f
                          : m * 0.5f;
                dgv = dc; rna = (z == 3) ? rnC : rnI;
            } else {
                mg = m; dgv = ds; rna = (z == 1) ? rnT : rnI;
            }
            aRn[ar] = rna; aDg[ar] = dgv; aMg[ar] = mg; aLab[ar] = labels[a];
            resIdx[ar] = (flag && mg < 0.16f) ? -1 : INT_MAX;
        }
        if (tid == 0) blockAcc = 0.0f;
    }
    __syncthreads();
    const int ty4  = (tid >> 4) * 4, tx4 = (tid & 15) * 4;
    const int lrow = tid >> 2,  lk4 = (tid & 3) * 4;
    int bandCols = 0, unresolved = 64;
    for (int jc = 0; jc < 2; ++jc) {
        int j0 = jc * 64;
        float acc[4][4];
        #pragma unroll
        for (int i = 0; i < 4; ++i)
            #pragma unroll
            for (int j = 0; j < 4; ++j) acc[i][j] = 0.0f;
        float bssq = 0.0f;
        for (int kc = 0; kc < ND; kc += 16) {
            __syncthreads();
            float4 va = *(const float4*)(A + (size_t)(a0 + lrow) * ND + kc + lk4);
            float4 vb = *(const float4*)(B + (size_t)(j0 + lrow) * ND + kc + lk4);
            As[lk4 + 0][lrow] = va.x; As[lk4 + 1][lrow] = va.y;
            As[lk4 + 2][lrow] = va.z; As[lk4 + 3][lrow] = va.w;
            Bs[lk4 + 0][lrow] = vb.x; Bs[lk4 + 1][lrow] = vb.y;
            Bs[lk4 + 2][lrow] = vb.z; Bs[lk4 + 3][lrow] = vb.w;
            bssq += vb.x*vb.x + vb.y*vb.y + vb.z*vb.z + vb.w*vb.w;
            __syncthreads();
            #pragma unroll
            for (int k = 0; k < 16; ++k) {
                float4 av = *(const float4*)&As[k][ty4];
                float4 bv = *(const float4*)&Bs[k][tx4];
                float ar[4] = {av.x, av.y, av.z, av.w};
                float br[4] = {bv.x, bv.y, bv.z, bv.w};
                #pragma unroll
                for (int i = 0; i < 4; ++i)
                    #pragma unroll
                    for (int j = 0; j < 4; ++j)
                        acc[i][j] = fmaf(ar[i], br[j], acc[i][j]);
            }
        }
        bssq += __shfl_xor(bssq, 1); bssq += __shfl_xor(bssq, 2);
        __syncthreads();
        if ((tid & 3) == 0) {
            colRn[lrow]  = 1.0f / (sqrtf(bssq) + 1e-8f);
            colLab[lrow] = labels[j0 + lrow];
        }
        if (tid < 64) prevIdx[tid] = resIdx[tid];
        __syncthreads();
        #pragma unroll
        for (int i = 0; i < 4; ++i) {
            int r = ty4 + i;
            if (prevIdx[r] != INT_MAX) continue;
            float dg = aDg[r], mgv = aMg[r], rna = aRn[r];
            int la = aLab[r];
            #pragma unroll
            for (int j = 0; j < 4; ++j) {
                int c = tx4 + j;
                if (colLab[c] == la) continue;
                float v  = acc[i][j] * rna * colRn[c];
                float lm = v - dg + mgv;
                if (lm > 0.0f && lm < mgv) atomicMin(&resIdx[r], j0 + c);
            }
        }
        __syncthreads();
        #pragma unroll
        for (int i = 0; i < 4; ++i) {
            int r = ty4 + i;
            if (prevIdx[r] != INT_MAX) continue;
            int w = resIdx[r];
            if (w == INT_MAX) continue;
            int c = w - j0 - tx4;
            if (c < 0 || c > 3) continue;
            float v  = acc[i][c] * aRn[r] * colRn[tx4 + c];
            float lm = v - aDg[r] + aMg[r];
            atomicAdd(&blockAcc, lm);
        }
        __syncthreads();
        if (tid == 0) cnt = 0;
        __syncthreads();
        if (tid < 64 && resIdx[tid] == INT_MAX) atomicAdd(&cnt, 1);
        __syncthreads();
        unresolved = cnt;
        bandCols = j0 + 64;
        __syncthreads();
        if (unresolved <= 8) break;
    }
    if (unresolved > 0) {
        if (tid == 0) sCnt = 0;
        __syncthreads();
        if (tid < 64 && resIdx[tid] == INT_MAX) {
            int pos = atomicAdd(&sCnt, 1);
            sList[pos] = tid;
        }
        __syncthreads();
        int total = sCnt;
        for (int g0 = 0; g0 < total; g0 += 8) {
            int u = min(8, total - g0);
            if (u == 1)      stragScan<1>(A, B, labels, a0, u, bandCols, sList, g0, aRn, aDg, aMg, aLab, sMin8, &doneMask, &blockAcc);
            else if (u == 2) stragScan<2>(A, B, labels, a0, u, bandCols, sList, g0, aRn, aDg, aMg, aLab, sMin8, &doneMask, &blockAcc);
            else if (u <= 4) stragScan<4>(A, B, labels, a0, u, bandCols, sList, g0, aRn, aDg, aMg, aLab, sMin8, &doneMask, &blockAcc);
            else             stragScan<8>(A, B, labels, a0, u, bandCols, sList, g0, aRn, aDg, aMg, aLab, sMin8, &doneMask, &blockAcc);
            __syncthreads();
        }
    }
    if (tid == 0 && blockAcc != 0.0f) {
        float scale = (z >= 2) ? betap[0] : 1.0f;
        atomicAdd(out, blockAcc * scale);
    }
}

// ===========================================================================

extern "C" void kernel_launch(void* const* d_in, const int* in_sizes, int n_in,
                              void* d_out, int out_size, void* d_ws, size_t ws_size,
                              hipStream_t stream) {
    const float* img    = (const float*)d_in[0];
    const float* txt    = (const float*)d_in[1];
    const float* cr     = (const float*)d_in[2];
    const int*   labels = (const int*)  d_in[3];
    const int*   flagp  = (const int*)  d_in[4];
    const float* marg   = (const float*)d_in[5];
    const float* betap  = (const float*)d_in[6];
    float* out = (float*)d_out;
    (void)in_sizes; (void)n_in;

    const size_t REQ = (size_t)(6 * NB) * 4 + (size_t)(4 * NB) * 4 + 64 +
                       (size_t)(4 * NB) * 4;
    if (ws_size >= REQ) {
        float* wf = (float*)d_ws;
        float* rnImg = wf + 0 * NB;
        float* rnTxt = wf + 1 * NB;
        float* rnCr  = wf + 2 * NB;
        float* dgSim = wf + 3 * NB;
        float* dgCr  = wf + 4 * NB;
        float* mgCr  = wf + 5 * NB;
        int* negIdx    = (int*)(wf + 6 * NB);
        int* stragCnt  = negIdx + 4 * NB;
        int* stragList = stragCnt + 16;

        stats_k<<<dim3(NB / 16),      dim3(256), 0, stream>>>(
            img, txt, cr, marg, flagp,
            rnImg, rnTxt, rnCr, dgSim, dgCr, mgCr, negIdx, stragCnt, out);
        band_k <<<dim3(NB / 64, 4),   dim3(256), 0, stream>>>(
            img, txt, cr, labels, flagp, marg, betap,
            rnImg, rnTxt, rnCr, dgSim, dgCr, mgCr, stragCnt, stragList, out);
        strag_k<<<dim3(16384),        dim3(256), 0, stream>>>(
            img, txt, cr, labels, rnImg, rnTxt, rnCr, dgSim, dgCr, marg, mgCr,
            stragCnt, stragList, negIdx);
        final_k<<<dim3(NB / 256, 4),  dim3(256), 0, stream>>>(
            img, txt, cr, rnImg, rnTxt, rnCr, dgSim, dgCr, marg, mgCr, betap,
            stragCnt, stragList, negIdx, out);
    } else {
        zero_k<<<dim3((out_size + 255) / 256), dim3(256), 0, stream>>>(out, out_size);
        mine_k<<<dim3(NB / 64, 4), dim3(256), 0, stream>>>(img, txt, cr, labels,
                                                           flagp, marg, betap, out);
    }
}